// Round 1
// baseline (1015.063 us; speedup 1.0000x reference)
//
#include <hip/hip_runtime.h>
#include <cstdint>
#include <cstddef>

typedef __attribute__((ext_vector_type(8))) short short8;
typedef __attribute__((ext_vector_type(4))) float f32x4;
typedef unsigned short ushort_t;

// ---------------- ws layout (bytes) ----------------
#define WBF_OFF   0u            // 512*64*64 bf16 (linear) = 4 MiB
#define KVH_OFF   4194304u      // 32768*128 bf16 (kh|vh per row) = 8 MiB
#define QH_OFF    12582912u     // 512*64 f32 (pre-scaled by 1/sqrt(8))
#define AVG_OFF   12713984u     // 512*64 f32 row means of mem_w
#define WEFF_OFF  12845056u     // 3 * 64*64 f32 combined projections
#define BEFF_OFF  12894208u     // 3 * 64 f32 combined biases
#define OACC_OFF  12894976u     // 8*512*8 f32 attention numerator accum
#define ESUM_OFF  13026048u     // 8*512 f32 softmax denominator accum
#define RATIO_OFF 13042432u     // 512*64 f32 (1 + attn_out/row_mean)
#define FLAG_OFF  13173504u     // int: nontrivial ln_g/ln_b flag

__device__ __forceinline__ float bf2f(ushort_t u) {
  union { unsigned int i; float f; } c; c.i = ((unsigned int)u) << 16; return c.f;
}
__device__ __forceinline__ ushort_t f2bf(float f) {
  union { float f; unsigned int i; } c; c.f = f;
  unsigned int x = c.i;
  x += 0x7FFFu + ((x >> 16) & 1u);   // round-to-nearest-even
  return (ushort_t)(x >> 16);
}

// ---------------- init: zero accumulators + flag ----------------
__global__ __launch_bounds__(256) void kinit(float* oacc, int* flag) {
  int gid = blockIdx.x * 256 + threadIdx.x;
  if (gid < 36864) oacc[gid] = 0.f;   // oacc (32768) + esum (4096), contiguous
  if (gid == 0) *flag = 0;
}

// ---------------- flag: detect nontrivial ln_g/ln_b ----------------
__global__ __launch_bounds__(256) void kflag(const float* __restrict__ g,
                                             const float* __restrict__ b, int* flag) {
  int gid = blockIdx.x * 256 + threadIdx.x;
  if (gid < 32768) {
    bool bad = (g[gid] != 1.0f) || (b[gid] != 0.0f);
    if (bad) atomicOr(flag, 1);
  }
}

// ---------------- prep: mem_w -> bf16 (linear) + row means ----------------
__global__ __launch_bounds__(256) void kprep(const float* __restrict__ mem_w,
                                             short* __restrict__ wbf,
                                             float* __restrict__ avg) {
  int gid = blockIdx.x * 256 + threadIdx.x;   // row index (m*64 + i), 32768 rows
  const float4* src = (const float4*)(mem_w + (size_t)gid * 64);
  int4* dst = (int4*)(wbf + (size_t)gid * 64);
  float sum = 0.f;
#pragma unroll
  for (int c = 0; c < 8; ++c) {
    float4 f0 = src[c * 2], f1 = src[c * 2 + 1];
    sum += f0.x + f0.y + f0.z + f0.w + f1.x + f1.y + f1.z + f1.w;
    union { ushort_t u[8]; int4 v; } pk;
    pk.u[0] = f2bf(f0.x); pk.u[1] = f2bf(f0.y); pk.u[2] = f2bf(f0.z); pk.u[3] = f2bf(f0.w);
    pk.u[4] = f2bf(f1.x); pk.u[5] = f2bf(f1.y); pk.u[6] = f2bf(f1.z); pk.u[7] = f2bf(f1.w);
    dst[c] = pk.v;
  }
  avg[gid] = sum * 0.015625f;
}

// ---------------- combined projection weights ----------------
// weff[mat][j][e] = sum_t in_proj_w[mat*64+j][t] * Wx[t][e]
// beff[mat][j]    = sum_t in_proj_w[mat*64+j][t] * bx[t] + in_proj_b[mat*64+j]
__global__ __launch_bounds__(256) void kweff(const float* __restrict__ in_proj_w,
                                             const float* __restrict__ in_proj_b,
                                             const float* __restrict__ Wq, const float* __restrict__ bq,
                                             const float* __restrict__ Wk, const float* __restrict__ bk,
                                             const float* __restrict__ Wv, const float* __restrict__ bv,
                                             float* __restrict__ weff, float* __restrict__ beff) {
  int gid = blockIdx.x * 256 + threadIdx.x;
  if (gid < 12288) {
    int mat = gid >> 12, j = (gid >> 6) & 63, e = gid & 63;
    const float* Wi = in_proj_w + ((size_t)(mat * 64 + j)) * 64;
    const float* Wx = (mat == 0) ? Wq : ((mat == 1) ? Wk : Wv);
    float acc = 0.f;
#pragma unroll 8
    for (int tt = 0; tt < 64; ++tt) acc = fmaf(Wi[tt], Wx[tt * 64 + e], acc);
    weff[gid] = acc;
  } else if (gid < 12288 + 192) {
    int k = gid - 12288; int mat = k >> 6, j = k & 63;
    const float* Wi = in_proj_w + ((size_t)(mat * 64 + j)) * 64;
    const float* bx = (mat == 0) ? bq : ((mat == 1) ? bk : bv);
    float acc = in_proj_b[mat * 64 + j];
#pragma unroll 8
    for (int tt = 0; tt < 64; ++tt) acc = fmaf(Wi[tt], bx[tt], acc);
    beff[k] = acc;
  }
}

// ---------------- qh = avg_w @ Wq_eff^T + bq_eff, scaled 1/sqrt(DH) --------
__global__ __launch_bounds__(256) void kqh(const float* __restrict__ avg,
                                           const float* __restrict__ weff,
                                           const float* __restrict__ beff,
                                           float* __restrict__ qh) {
  int gid = blockIdx.x * 256 + threadIdx.x;   // 32768 = 512*64
  int m = gid >> 6, j = gid & 63;
  const float* ar = avg + (size_t)m * 64;
  const float* wr = weff + (size_t)j * 64;
  float acc = beff[j];
#pragma unroll 8
  for (int e = 0; e < 64; ++e) acc = fmaf(ar[e], wr[e], acc);
  qh[gid] = acc * 0.35355339059327373f;
}

// ---------------- the sequential memory scan ----------------
// block = 256 threads (4 waves), 64 rows; 512 steps of
//   h <- LN(relu(h @ W_m^T)) ; swapped-operand MFMA: C'[e',r] = W·h^T
__global__ __launch_bounds__(256) void kscan(
    const float* __restrict__ x, const short* __restrict__ wbf,
    const float* __restrict__ ln_g, const float* __restrict__ ln_b,
    const int* __restrict__ flagp, float* __restrict__ mem_out) {
  __shared__ short hbuf[64 * 64];        // h rows (bf16, XOR-swizzled), wave-private rows
  __shared__ short wlds[2][64 * 64];     // W double buffer (bf16, XOR-swizzled)
  const int t = threadIdx.x;
  const int wv = t >> 6;
  const int lane = t & 63;
  const int lcol = lane & 15;
  const int lg = lane >> 4;
  const int blk = blockIdx.x;
  const int gb = *flagp;

  // prologue: x rows -> hbuf
  {
    const int row = t >> 2;
    const int q = t & 3;
    const float4* xp = (const float4*)(x + ((size_t)(blk * 64 + row)) * 64 + q * 16);
    float4 f0 = xp[0], f1 = xp[1], f2 = xp[2], f3 = xp[3];
    union { ushort_t u[8]; int4 v; } p0, p1;
    p0.u[0] = f2bf(f0.x); p0.u[1] = f2bf(f0.y); p0.u[2] = f2bf(f0.z); p0.u[3] = f2bf(f0.w);
    p0.u[4] = f2bf(f1.x); p0.u[5] = f2bf(f1.y); p0.u[6] = f2bf(f1.z); p0.u[7] = f2bf(f1.w);
    p1.u[0] = f2bf(f2.x); p1.u[1] = f2bf(f2.y); p1.u[2] = f2bf(f2.z); p1.u[3] = f2bf(f2.w);
    p1.u[4] = f2bf(f3.x); p1.u[5] = f2bf(f3.y); p1.u[6] = f2bf(f3.z); p1.u[7] = f2bf(f3.w);
    const int sw = (row & 7) << 4;
    *(int4*)((char*)hbuf + row * 128 + ((q * 32) ^ sw)) = p0.v;
    *(int4*)((char*)hbuf + row * 128 + ((q * 32 + 16) ^ sw)) = p1.v;
  }
  // stage W[0]
  {
    const int4* src = (const int4*)wbf;
    int4 a = src[t], b2 = src[t + 256];
    int o0 = t * 16, o1 = 4096 + t * 16;
    *(int4*)((char*)wlds[0] + (o0 ^ (((o0 >> 7) & 7) << 4))) = a;
    *(int4*)((char*)wlds[0] + (o1 ^ (((o1 >> 7) & 7) << 4))) = b2;
  }
  __syncthreads();

  const int r = wv * 16 + lcol;                    // this lane's h row (B and C col)
  const int rsw = (r & 7) << 4;
  const int hrd0 = r * 128 + ((lg * 16) ^ rsw);    // B-frag k-tile 0
  const int hrd1 = r * 128 + ((lg * 16 + 64) ^ rsw);
  const int wsw = (lcol & 7) << 4;
  const int wrd0 = lcol * 128 + ((lg * 16) ^ wsw); // A-frag (W), + mt*2048
  const int wrd1 = lcol * 128 + ((lg * 16 + 64) ^ wsw);
  int hwr[4];
#pragma unroll
  for (int mt = 0; mt < 4; ++mt) hwr[mt] = r * 128 + (((mt * 32) + lg * 8) ^ rsw);
  const int so0 = (t * 16) ^ ((((t * 16) >> 7) & 7) << 4);
  const int so1 = (4096 + t * 16) ^ ((((4096 + t * 16) >> 7) & 7) << 4);
  const f32x4 z4 = {0.f, 0.f, 0.f, 0.f};

  int cur = 0;
  for (int m = 0; m < 512; ++m) {
    int4 s0, s1;
    if (m < 511) {                                  // T14: issue early, write late
      const int4* src = (const int4*)(wbf + (size_t)(m + 1) * 4096);
      s0 = src[t]; s1 = src[t + 256];
    }
    const char* wb = (const char*)wlds[cur];
    short8 hf0 = *(const short8*)((const char*)hbuf + hrd0);
    short8 hf1 = *(const short8*)((const char*)hbuf + hrd1);
    f32x4 acc[4];
#pragma unroll
    for (int mt = 0; mt < 4; ++mt) {
      short8 a0 = *(const short8*)(wb + wrd0 + mt * 2048);
      short8 a1 = *(const short8*)(wb + wrd1 + mt * 2048);
      acc[mt] = __builtin_amdgcn_mfma_f32_16x16x32_bf16(a0, hf0, z4, 0, 0, 0);
      acc[mt] = __builtin_amdgcn_mfma_f32_16x16x32_bf16(a1, hf1, acc[mt], 0, 0, 0);
    }
    // relu + LN stats (row r is lane-local up to lanes {l, l^16, l^32, l^48})
    float v[16];
    float s = 0.f, sq = 0.f;
#pragma unroll
    for (int mt = 0; mt < 4; ++mt)
#pragma unroll
      for (int rg = 0; rg < 4; ++rg) {
        float zz = fmaxf(acc[mt][rg], 0.f);
        v[mt * 4 + rg] = zz;
        s += zz;
        sq = fmaf(zz, zz, sq);
      }
    s += __shfl_xor(s, 16);  s += __shfl_xor(s, 32);
    sq += __shfl_xor(sq, 16); sq += __shfl_xor(sq, 32);
    const float mean = s * 0.015625f;
    const float var = fmaf(sq, 0.015625f, -mean * mean);
    const float rs = rsqrtf(var + 1e-5f);
    const float cc = -mean * rs;
    if (gb) {   // general ln_g/ln_b path (not taken for setup_inputs data)
#pragma unroll
      for (int mt = 0; mt < 4; ++mt) {
        float4 gg = *(const float4*)(ln_g + m * 64 + mt * 16 + lg * 4);
        float4 bb = *(const float4*)(ln_b + m * 64 + mt * 16 + lg * 4);
        union { ushort_t u[4]; uint2 q2; } pk;
        pk.u[0] = f2bf(fmaf(fmaf(v[mt * 4 + 0], rs, cc), gg.x, bb.x));
        pk.u[1] = f2bf(fmaf(fmaf(v[mt * 4 + 1], rs, cc), gg.y, bb.y));
        pk.u[2] = f2bf(fmaf(fmaf(v[mt * 4 + 2], rs, cc), gg.z, bb.z));
        pk.u[3] = f2bf(fmaf(fmaf(v[mt * 4 + 3], rs, cc), gg.w, bb.w));
        *(uint2*)((char*)hbuf + hwr[mt]) = pk.q2;
      }
    } else {
#pragma unroll
      for (int mt = 0; mt < 4; ++mt) {
        union { ushort_t u[4]; uint2 q2; } pk;
        pk.u[0] = f2bf(fmaf(v[mt * 4 + 0], rs, cc));
        pk.u[1] = f2bf(fmaf(v[mt * 4 + 1], rs, cc));
        pk.u[2] = f2bf(fmaf(v[mt * 4 + 2], rs, cc));
        pk.u[3] = f2bf(fmaf(v[mt * 4 + 3], rs, cc));
        *(uint2*)((char*)hbuf + hwr[mt]) = pk.q2;
      }
    }
    if (m < 511) {
      char* wn = (char*)wlds[cur ^ 1];
      *(int4*)(wn + so0) = s0;
      *(int4*)(wn + so1) = s1;
    }
    __syncthreads();   // single barrier: publishes wlds[cur^1]; h rows are wave-private
    cur ^= 1;
  }

  // epilogue: hbuf (bf16) -> mem_out (f32, coalesced)
#pragma unroll
  for (int p = 0; p < 4; ++p) {
    const int row = p * 16 + (t >> 4);
    const int e0 = (t & 15) * 4;
    const int boff = row * 128 + ((e0 * 2) ^ ((row & 7) << 4));
    uint2 dv = *(const uint2*)((const char*)hbuf + boff);
    float4 o;
    o.x = bf2f((ushort_t)(dv.x & 0xFFFFu));
    o.y = bf2f((ushort_t)(dv.x >> 16));
    o.z = bf2f((ushort_t)(dv.y & 0xFFFFu));
    o.w = bf2f((ushort_t)(dv.y >> 16));
    ((float4*)(mem_out + ((size_t)(blk * 64 + row)) * 64))[t & 15] = o;
  }
}

// ---------------- kh/vh = mem_out @ W{k,v}_eff^T + b, stored bf16 ----------
__global__ __launch_bounds__(256) void kkv(const float* __restrict__ mem_out,
                                           const float* __restrict__ weff,
                                           const float* __restrict__ beff,
                                           short* __restrict__ khvh) {
  __shared__ short kvs[128 * 128];
  const int t = threadIdx.x;
  const int nl = t >> 1;
  const int jh = (t & 1) * 32;
  const int n = blockIdx.x * 128 + nl;
  float mo[64];
  const float4* mop = (const float4*)(mem_out + (size_t)n * 64);
#pragma unroll
  for (int c = 0; c < 16; ++c) {
    float4 f = mop[c];
    mo[c * 4] = f.x; mo[c * 4 + 1] = f.y; mo[c * 4 + 2] = f.z; mo[c * 4 + 3] = f.w;
  }
  const float* wk = weff + 4096;
  const float* wvp = weff + 8192;
  const float* bk = beff + 64;
  const float* bv = beff + 128;
  for (int jj = 0; jj < 32; ++jj) {
    const int j = jh + jj;
    float ak = bk[j], av = bv[j];
    const float* wkr = wk + (size_t)j * 64;
    const float* wvr = wvp + (size_t)j * 64;
#pragma unroll 8
    for (int e = 0; e < 64; ++e) { ak = fmaf(mo[e], wkr[e], ak); av = fmaf(mo[e], wvr[e], av); }
    kvs[nl * 128 + j] = (short)f2bf(ak);
    kvs[nl * 128 + 64 + j] = (short)f2bf(av);
  }
  __syncthreads();
  int4* dst = (int4*)(khvh + (size_t)blockIdx.x * 16384);
  const int4* srcl = (const int4*)kvs;
#pragma unroll
  for (int c = 0; c < 8; ++c) dst[t + c * 256] = srcl[t + c * 256];
}

// ---------------- attention accumulation (no-max softmax, scores tiny) -----
__global__ __launch_bounds__(512) void kattn(const short* __restrict__ khvh,
                                             const float* __restrict__ qh,
                                             float* __restrict__ oacc,
                                             float* __restrict__ esum) {
  __shared__ short kv[128 * 128];
  const int t = threadIdx.x;
  const int hh = t >> 6;     // whole wave shares one head -> LDS broadcasts
  const int ms = t & 63;
  {
    const int4* src = (const int4*)(khvh + (size_t)blockIdx.x * 16384);
    int4* d = (int4*)kv;
#pragma unroll
    for (int c = 0; c < 4; ++c) d[t + c * 512] = src[t + c * 512];
  }
  __syncthreads();
  float q[8][8], o[8][8], es[8];
#pragma unroll
  for (int i = 0; i < 8; ++i) {
    const float4* qp = (const float4*)(qh + ((size_t)(ms + i * 64)) * 64 + hh * 8);
    float4 q0 = qp[0], q1 = qp[1];
    q[i][0] = q0.x; q[i][1] = q0.y; q[i][2] = q0.z; q[i][3] = q0.w;
    q[i][4] = q1.x; q[i][5] = q1.y; q[i][6] = q1.z; q[i][7] = q1.w;
    es[i] = 0.f;
#pragma unroll
    for (int d = 0; d < 8; ++d) o[i][d] = 0.f;
  }
  for (int n = 0; n < 128; ++n) {
    const short8 kraw = *(const short8*)(kv + n * 128 + hh * 8);
    const short8 vraw = *(const short8*)(kv + n * 128 + 64 + hh * 8);
    float kf[8], vf[8];
#pragma unroll
    for (int d = 0; d < 8; ++d) {
      kf[d] = bf2f((ushort_t)kraw[d]);
      vf[d] = bf2f((ushort_t)vraw[d]);
    }
#pragma unroll
    for (int i = 0; i < 8; ++i) {
      float s = 0.f;
#pragma unroll
      for (int d = 0; d < 8; ++d) s = fmaf(q[i][d], kf[d], s);
      float p = __expf(s);
      es[i] += p;
#pragma unroll
      for (int d = 0; d < 8; ++d) o[i][d] = fmaf(p, vf[d], o[i][d]);
    }
  }
#pragma unroll
  for (int i = 0; i < 8; ++i) {
    const int m = ms + i * 64;
    atomicAdd(&esum[hh * 512 + m], es[i]);
#pragma unroll
    for (int d = 0; d < 8; ++d) atomicAdd(&oacc[((size_t)(hh * 512 + m)) * 8 + d], o[i][d]);
  }
}

// ---------------- attn_out + ratio ----------------
__global__ __launch_bounds__(256) void kratio(const float* __restrict__ oacc,
                                              const float* __restrict__ esum,
                                              const float* __restrict__ out_w,
                                              const float* __restrict__ out_b,
                                              const float* __restrict__ avg,
                                              float* __restrict__ ratio) {
  int gid = blockIdx.x * 256 + threadIdx.x;  // 32768 = 512*64
  int m = gid >> 6, e = gid & 63;
  float of[64];
#pragma unroll
  for (int h = 0; h < 8; ++h) {
    float inv = 1.f / esum[h * 512 + m];
    const float* op = oacc + ((size_t)(h * 512 + m)) * 8;
#pragma unroll
    for (int d = 0; d < 8; ++d) of[h * 8 + d] = op[d] * inv;
  }
  float a = out_b[e];
  const float* wr = out_w + (size_t)e * 64;
#pragma unroll 8
  for (int j = 0; j < 64; ++j) a = fmaf(of[j], wr[j], a);
  ratio[gid] = 1.f + a / avg[gid];
}

// ---------------- new_mem_w = mem_w * ratio ----------------
__global__ __launch_bounds__(256) void kfinal(const float* __restrict__ mem_w,
                                              const float* __restrict__ ratio,
                                              float* __restrict__ out1) {
  int gid = blockIdx.x * 256 + threadIdx.x;  // 524288 float4s
  float rr = ratio[gid >> 4];
  float4 w = ((const float4*)mem_w)[gid];
  float4 o; o.x = w.x * rr; o.y = w.y * rr; o.z = w.z * rr; o.w = w.w * rr;
  ((float4*)out1)[gid] = o;
}

extern "C" void kernel_launch(void* const* d_in, const int* in_sizes, int n_in,
                              void* d_out, int out_size, void* d_ws, size_t ws_size,
                              hipStream_t stream) {
  (void)in_sizes; (void)n_in; (void)out_size; (void)ws_size;
  const float* x         = (const float*)d_in[0];
  const float* mem_w     = (const float*)d_in[1];
  const float* ln_g      = (const float*)d_in[2];
  const float* ln_b      = (const float*)d_in[3];
  const float* Wq        = (const float*)d_in[4];
  const float* bq        = (const float*)d_in[5];
  const float* Wk        = (const float*)d_in[6];
  const float* bk        = (const float*)d_in[7];
  const float* Wv        = (const float*)d_in[8];
  const float* bv        = (const float*)d_in[9];
  const float* in_proj_w = (const float*)d_in[10];
  const float* in_proj_b = (const float*)d_in[11];
  const float* out_w     = (const float*)d_in[12];
  const float* out_b     = (const float*)d_in[13];

  float* dout = (float*)d_out;
  char* ws = (char*)d_ws;
  short* wbf   = (short*)(ws + WBF_OFF);
  short* khvh  = (short*)(ws + KVH_OFF);
  float* qh    = (float*)(ws + QH_OFF);
  float* avg   = (float*)(ws + AVG_OFF);
  float* weff  = (float*)(ws + WEFF_OFF);
  float* beff  = (float*)(ws + BEFF_OFF);
  float* oacc  = (float*)(ws + OACC_OFF);
  float* esum  = (float*)(ws + ESUM_OFF);
  float* ratio = (float*)(ws + RATIO_OFF);
  int*   flag  = (int*)(ws + FLAG_OFF);

  float* mem_out = dout;              // output 0: (32768, 64)
  float* out1    = dout + 2097152;    // output 1: (512, 64, 64)

  kinit<<<144, 256, 0, stream>>>(oacc, flag);
  kflag<<<128, 256, 0, stream>>>(ln_g, ln_b, flag);
  kprep<<<128, 256, 0, stream>>>(mem_w, wbf, avg);
  kweff<<<49, 256, 0, stream>>>(in_proj_w, in_proj_b, Wq, bq, Wk, bk, Wv, bv, weff, beff);
  kqh<<<128, 256, 0, stream>>>(avg, weff, beff, qh);
  kscan<<<512, 256, 0, stream>>>(x, wbf, ln_g, ln_b, flag, mem_out);
  kkv<<<256, 256, 0, stream>>>(mem_out, weff, beff, khvh);
  kattn<<<256, 512, 0, stream>>>(khvh, qh, oacc, esum);
  kratio<<<128, 256, 0, stream>>>(oacc, esum, out_w, out_b, avg, ratio);
  kfinal<<<2048, 256, 0, stream>>>(mem_w, ratio, out1);
}

// Round 3
// 696.971 us; speedup vs baseline: 1.4564x; 1.4564x over previous
//
#include <hip/hip_runtime.h>
#include <hip/hip_bf16.h>
#include <cstdint>
#include <cstddef>

typedef __attribute__((ext_vector_type(8))) short short8;
typedef __attribute__((ext_vector_type(4))) float f32x4;
typedef unsigned short ushort_t;

// ---------------- ws layout (bytes) ----------------
#define WBF_OFF   0u            // 512*64*64 bf16 (linear) = 4 MiB
#define KVH_OFF   4194304u      // 32768*128 bf16 (kh|vh per row) = 8 MiB
#define QH_OFF    12582912u     // 512*64 f32 (pre-scaled by 1/sqrt(8))
#define AVG_OFF   12713984u     // 512*64 f32 row means of mem_w
#define WEFF_OFF  12845056u     // 3 * 64*64 f32 combined projections
#define BEFF_OFF  12894208u     // 3 * 64 f32 combined biases
#define OACC_OFF  12894976u     // 8*512*8 f32 attention numerator
#define ESUM_OFF  13026048u     // 8*512 f32 softmax denominator
#define RATIO_OFF 13042432u     // 512*64 f32 (1 + attn_out/row_mean)
#define FLAG_OFF  13173504u     // int: nontrivial ln_g/ln_b flag
#define PO_OFF    13180928u     // 64 chunks * 32768 f32 partial O = 8 MiB
#define PE_OFF    21569536u     // 64 chunks * 4096 f32 partial esum = 1 MiB
#define WS_NEED   22618112ull   // bytes required for the partial scheme
#define NCH 64                  // key chunks (512 keys each)

__device__ __forceinline__ float bf2f(ushort_t u) {
  union { unsigned int i; float f; } c; c.i = ((unsigned int)u) << 16; return c.f;
}
__device__ __forceinline__ unsigned pk2bf(float a, float b) {
  __hip_bfloat162 h = __float22bfloat162_rn(make_float2(a, b));
  unsigned u;
  __builtin_memcpy(&u, &h, 4);
  return u;
}
__device__ __forceinline__ ushort_t f2bf1(float f) {
  union { float f; unsigned int i; } c; c.f = f;
  unsigned int x = c.i;
  x += 0x7FFFu + ((x >> 16) & 1u);
  return (ushort_t)(x >> 16);
}

// ---------------- init: zero accumulators + flag ----------------
__global__ __launch_bounds__(256) void kinit(float* oacc, int* flag) {
  int gid = blockIdx.x * 256 + threadIdx.x;
  if (gid < 36864) oacc[gid] = 0.f;   // oacc (32768) + esum (4096), contiguous
  if (gid == 0) *flag = 0;
}

// ---------------- flag: detect nontrivial ln_g/ln_b ----------------
__global__ __launch_bounds__(256) void kflag(const float* __restrict__ g,
                                             const float* __restrict__ b, int* flag) {
  int gid = blockIdx.x * 256 + threadIdx.x;
  if (gid < 32768) {
    bool bad = (g[gid] != 1.0f) || (b[gid] != 0.0f);
    if (bad) atomicOr(flag, 1);
  }
}

// ---------------- prep: mem_w -> bf16 (linear) + row means ----------------
__global__ __launch_bounds__(256) void kprep(const float* __restrict__ mem_w,
                                             short* __restrict__ wbf,
                                             float* __restrict__ avg) {
  int gid = blockIdx.x * 256 + threadIdx.x;   // row index (m*64 + i), 32768 rows
  const float4* src = (const float4*)(mem_w + (size_t)gid * 64);
  int4* dst = (int4*)(wbf + (size_t)gid * 64);
  float sum = 0.f;
#pragma unroll
  for (int c = 0; c < 8; ++c) {
    float4 f0 = src[c * 2], f1 = src[c * 2 + 1];
    sum += f0.x + f0.y + f0.z + f0.w + f1.x + f1.y + f1.z + f1.w;
    int4 pk;
    pk.x = (int)pk2bf(f0.x, f0.y); pk.y = (int)pk2bf(f0.z, f0.w);
    pk.z = (int)pk2bf(f1.x, f1.y); pk.w = (int)pk2bf(f1.z, f1.w);
    dst[c] = pk;
  }
  avg[gid] = sum * 0.015625f;
}

// ---------------- combined projection weights ----------------
__global__ __launch_bounds__(256) void kweff(const float* __restrict__ in_proj_w,
                                             const float* __restrict__ in_proj_b,
                                             const float* __restrict__ Wq, const float* __restrict__ bq,
                                             const float* __restrict__ Wk, const float* __restrict__ bk,
                                             const float* __restrict__ Wv, const float* __restrict__ bv,
                                             float* __restrict__ weff, float* __restrict__ beff) {
  int gid = blockIdx.x * 256 + threadIdx.x;
  if (gid < 12288) {
    int mat = gid >> 12, j = (gid >> 6) & 63, e = gid & 63;
    const float* Wi = in_proj_w + ((size_t)(mat * 64 + j)) * 64;
    const float* Wx = (mat == 0) ? Wq : ((mat == 1) ? Wk : Wv);
    float acc = 0.f;
#pragma unroll 8
    for (int tt = 0; tt < 64; ++tt) acc = fmaf(Wi[tt], Wx[tt * 64 + e], acc);
    weff[gid] = acc;
  } else if (gid < 12288 + 192) {
    int k = gid - 12288; int mat = k >> 6, j = k & 63;
    const float* Wi = in_proj_w + ((size_t)(mat * 64 + j)) * 64;
    const float* bx = (mat == 0) ? bq : ((mat == 1) ? bk : bv);
    float acc = in_proj_b[mat * 64 + j];
#pragma unroll 8
    for (int tt = 0; tt < 64; ++tt) acc = fmaf(Wi[tt], bx[tt], acc);
    beff[k] = acc;
  }
}

// ---------------- qh = avg_w @ Wq_eff^T + bq_eff, scaled 1/sqrt(DH) --------
__global__ __launch_bounds__(256) void kqh(const float* __restrict__ avg,
                                           const float* __restrict__ weff,
                                           const float* __restrict__ beff,
                                           float* __restrict__ qh) {
  int gid = blockIdx.x * 256 + threadIdx.x;   // 32768 = 512*64
  int m = gid >> 6, j = gid & 63;
  const float* ar = avg + (size_t)m * 64;
  const float* wr = weff + (size_t)j * 64;
  float acc = beff[j];
#pragma unroll 8
  for (int e = 0; e < 64; ++e) acc = fmaf(ar[e], wr[e], acc);
  qh[gid] = acc * 0.35355339059327373f;
}

// ---------------- the sequential memory scan ----------------
// block = 512 threads (8 waves), 128 rows; W staged once per CU per step
__global__ __launch_bounds__(512) void kscan(
    const float* __restrict__ x, const short* __restrict__ wbf,
    const float* __restrict__ ln_g, const float* __restrict__ ln_b,
    const int* __restrict__ flagp, float* __restrict__ mem_out) {
  __shared__ short hbuf[128 * 64];       // 128 h rows (bf16, XOR-swizzled)
  __shared__ short wlds[2][64 * 64];     // W double buffer (bf16, XOR-swizzled)
  const int t = threadIdx.x;
  const int wv = t >> 6;
  const int lane = t & 63;
  const int lcol = lane & 15;
  const int lg = lane >> 4;
  const int blk = blockIdx.x;
  const int gb = *flagp;

  // prologue: 128 x rows -> hbuf
  {
    const int row = t >> 2;
    const int q = t & 3;
    const float4* xp = (const float4*)(x + ((size_t)(blk * 128 + row)) * 64 + q * 16);
    float4 f0 = xp[0], f1 = xp[1], f2 = xp[2], f3 = xp[3];
    int4 p0, p1;
    p0.x = (int)pk2bf(f0.x, f0.y); p0.y = (int)pk2bf(f0.z, f0.w);
    p0.z = (int)pk2bf(f1.x, f1.y); p0.w = (int)pk2bf(f1.z, f1.w);
    p1.x = (int)pk2bf(f2.x, f2.y); p1.y = (int)pk2bf(f2.z, f2.w);
    p1.z = (int)pk2bf(f3.x, f3.y); p1.w = (int)pk2bf(f3.z, f3.w);
    const int sw = (row & 7) << 4;
    *(int4*)((char*)hbuf + row * 128 + ((q * 32) ^ sw)) = p0;
    *(int4*)((char*)hbuf + row * 128 + ((q * 32 + 16) ^ sw)) = p1;
  }
  // stage W[0]: 512 threads x 16B = 8KB
  {
    const int4* src = (const int4*)wbf;
    int4 a = src[t];
    int o0 = t * 16;
    *(int4*)((char*)wlds[0] + (o0 ^ (((o0 >> 7) & 7) << 4))) = a;
  }
  __syncthreads();

  const int r = wv * 16 + lcol;                    // this lane's h row (0..127)
  const int rsw = (r & 7) << 4;
  const int hrd0 = r * 128 + ((lg * 16) ^ rsw);    // B-frag k-tile 0
  const int hrd1 = r * 128 + ((lg * 16 + 64) ^ rsw);
  const int wsw = (lcol & 7) << 4;
  const int wrd0 = lcol * 128 + ((lg * 16) ^ wsw); // A-frag (W), + mt*2048
  const int wrd1 = lcol * 128 + ((lg * 16 + 64) ^ wsw);
  int hwr[4];
#pragma unroll
  for (int mt = 0; mt < 4; ++mt) hwr[mt] = r * 128 + (((mt * 32) + lg * 8) ^ rsw);
  const int so0 = (t * 16) ^ ((((t * 16) >> 7) & 7) << 4);
  const f32x4 z4 = {0.f, 0.f, 0.f, 0.f};

  int cur = 0;
  for (int m = 0; m < 512; ++m) {
    int4 s0;
    if (m < 511) {                                  // T14: issue early, write late
      s0 = ((const int4*)(wbf + (size_t)(m + 1) * 4096))[t];
    }
    const char* wb = (const char*)wlds[cur];
    short8 hf0 = *(const short8*)((const char*)hbuf + hrd0);
    short8 hf1 = *(const short8*)((const char*)hbuf + hrd1);
    f32x4 acc[4];
#pragma unroll
    for (int mt = 0; mt < 4; ++mt) {
      short8 a0 = *(const short8*)(wb + wrd0 + mt * 2048);
      short8 a1 = *(const short8*)(wb + wrd1 + mt * 2048);
      acc[mt] = __builtin_amdgcn_mfma_f32_16x16x32_bf16(a0, hf0, z4, 0, 0, 0);
      acc[mt] = __builtin_amdgcn_mfma_f32_16x16x32_bf16(a1, hf1, acc[mt], 0, 0, 0);
    }
    // relu + LN stats (row r spread over lanes {l, l^16, l^32, l^48})
    float v[16];
    float s = 0.f, sq = 0.f;
#pragma unroll
    for (int mt = 0; mt < 4; ++mt)
#pragma unroll
      for (int rg = 0; rg < 4; ++rg) {
        float zz = fmaxf(acc[mt][rg], 0.f);
        v[mt * 4 + rg] = zz;
        s += zz;
        sq = fmaf(zz, zz, sq);
      }
    s += __shfl_xor(s, 16);  s += __shfl_xor(s, 32);
    sq += __shfl_xor(sq, 16); sq += __shfl_xor(sq, 32);
    const float mean = s * 0.015625f;
    const float var = fmaf(sq, 0.015625f, -mean * mean);
    const float rs = rsqrtf(var + 1e-5f);
    const float cc = -mean * rs;
    if (gb) {   // general ln_g/ln_b path (not taken for setup_inputs data)
#pragma unroll
      for (int mt = 0; mt < 4; ++mt) {
        float4 gg = *(const float4*)(ln_g + m * 64 + mt * 16 + lg * 4);
        float4 bb = *(const float4*)(ln_b + m * 64 + mt * 16 + lg * 4);
        uint2 q2;
        q2.x = pk2bf(fmaf(fmaf(v[mt * 4 + 0], rs, cc), gg.x, bb.x),
                     fmaf(fmaf(v[mt * 4 + 1], rs, cc), gg.y, bb.y));
        q2.y = pk2bf(fmaf(fmaf(v[mt * 4 + 2], rs, cc), gg.z, bb.z),
                     fmaf(fmaf(v[mt * 4 + 3], rs, cc), gg.w, bb.w));
        *(uint2*)((char*)hbuf + hwr[mt]) = q2;
      }
    } else {
#pragma unroll
      for (int mt = 0; mt < 4; ++mt) {
        uint2 q2;
        q2.x = pk2bf(fmaf(v[mt * 4 + 0], rs, cc), fmaf(v[mt * 4 + 1], rs, cc));
        q2.y = pk2bf(fmaf(v[mt * 4 + 2], rs, cc), fmaf(v[mt * 4 + 3], rs, cc));
        *(uint2*)((char*)hbuf + hwr[mt]) = q2;
      }
    }
    if (m < 511) {
      *(int4*)((char*)wlds[cur ^ 1] + so0) = s0;
    }
    __syncthreads();   // publishes wlds[cur^1]; h rows are wave-private
    cur ^= 1;
  }

  // epilogue: hbuf (bf16) -> mem_out (f32, coalesced)
#pragma unroll
  for (int p = 0; p < 4; ++p) {
    const int row = p * 32 + (t >> 4);
    const int e0 = (t & 15) * 4;
    const int boff = row * 128 + ((e0 * 2) ^ ((row & 7) << 4));
    uint2 dv = *(const uint2*)((const char*)hbuf + boff);
    float4 o;
    o.x = bf2f((ushort_t)(dv.x & 0xFFFFu));
    o.y = bf2f((ushort_t)(dv.x >> 16));
    o.z = bf2f((ushort_t)(dv.y & 0xFFFFu));
    o.w = bf2f((ushort_t)(dv.y >> 16));
    ((float4*)(mem_out + ((size_t)(blk * 128 + row)) * 64))[t & 15] = o;
  }
}

// ---------------- kh/vh = mem_out @ W{k,v}_eff^T + b, stored bf16 ----------
__global__ __launch_bounds__(256) void kkv(const float* __restrict__ mem_out,
                                           const float* __restrict__ weff,
                                           const float* __restrict__ beff,
                                           short* __restrict__ khvh) {
  __shared__ short kvs[128 * 128];
  const int t = threadIdx.x;
  const int nl = t >> 1;
  const int jh = (t & 1) * 32;
  const int n = blockIdx.x * 128 + nl;
  float mo[64];
  const float4* mop = (const float4*)(mem_out + (size_t)n * 64);
#pragma unroll
  for (int c = 0; c < 16; ++c) {
    float4 f = mop[c];
    mo[c * 4] = f.x; mo[c * 4 + 1] = f.y; mo[c * 4 + 2] = f.z; mo[c * 4 + 3] = f.w;
  }
  const float* wk = weff + 4096;
  const float* wvp = weff + 8192;
  const float* bk = beff + 64;
  const float* bv = beff + 128;
  for (int jj = 0; jj < 32; ++jj) {
    const int j = jh + jj;
    float ak = bk[j], av = bv[j];
    const float* wkr = wk + (size_t)j * 64;
    const float* wvr = wvp + (size_t)j * 64;
#pragma unroll 8
    for (int e = 0; e < 64; ++e) { ak = fmaf(mo[e], wkr[e], ak); av = fmaf(mo[e], wvr[e], av); }
    kvs[nl * 128 + j] = (short)f2bf1(ak);
    kvs[nl * 128 + 64 + j] = (short)f2bf1(av);
  }
  __syncthreads();
  int4* dst = (int4*)(khvh + (size_t)blockIdx.x * 16384);
  const int4* srcl = (const int4*)kvs;
#pragma unroll
  for (int c = 0; c < 8; ++c) dst[t + c * 256] = srcl[t + c * 256];
}

// ---------------- attention, atomic-free two-stage ----------------
// grid = NCH*4 blocks x 512 thr; block (c,mc): keys [c*512,c*512+512),
// thread (h=t>>6, ml=t&63) owns queries m0=mc*128+ml and m1=m0+64.
__global__ __launch_bounds__(512) void kattn2(const short* __restrict__ khvh,
                                              const float* __restrict__ qh,
                                              float* __restrict__ pO,
                                              float* __restrict__ pE) {
  __shared__ short kv[128 * 128];   // 128-key tile (K|V interleaved rows)
  const int t = threadIdx.x;
  const int hh = t >> 6;
  const int ml = t & 63;
  const int c = blockIdx.x >> 2;
  const int mc = blockIdx.x & 3;
  const int m0 = mc * 128 + ml;
  const int m1 = m0 + 64;
  float q0[8], q1[8], o0[8], o1[8];
  float e0 = 0.f, e1 = 0.f;
  {
    const float4* qp0 = (const float4*)(qh + (size_t)m0 * 64 + hh * 8);
    const float4* qp1 = (const float4*)(qh + (size_t)m1 * 64 + hh * 8);
    float4 a = qp0[0], b = qp0[1], cc2 = qp1[0], d2 = qp1[1];
    q0[0]=a.x; q0[1]=a.y; q0[2]=a.z; q0[3]=a.w; q0[4]=b.x; q0[5]=b.y; q0[6]=b.z; q0[7]=b.w;
    q1[0]=cc2.x; q1[1]=cc2.y; q1[2]=cc2.z; q1[3]=cc2.w; q1[4]=d2.x; q1[5]=d2.y; q1[6]=d2.z; q1[7]=d2.w;
#pragma unroll
    for (int d = 0; d < 8; ++d) { o0[d] = 0.f; o1[d] = 0.f; }
  }
  for (int tile = 0; tile < 4; ++tile) {
    if (tile) __syncthreads();
    const int4* src = (const int4*)(khvh + ((size_t)(c * 512 + tile * 128)) * 128);
    int4* dl = (int4*)kv;
#pragma unroll
    for (int u = 0; u < 4; ++u) dl[t + u * 512] = src[t + u * 512];
    __syncthreads();
    for (int n = 0; n < 128; ++n) {
      const short8 kraw = *(const short8*)(kv + n * 128 + hh * 8);
      const short8 vraw = *(const short8*)(kv + n * 128 + 64 + hh * 8);
      float kf[8], vf[8];
#pragma unroll
      for (int d = 0; d < 8; ++d) {
        kf[d] = bf2f((ushort_t)kraw[d]);
        vf[d] = bf2f((ushort_t)vraw[d]);
      }
      float s0 = 0.f, s1 = 0.f;
#pragma unroll
      for (int d = 0; d < 8; ++d) { s0 = fmaf(q0[d], kf[d], s0); s1 = fmaf(q1[d], kf[d], s1); }
      float p0 = __expf(s0), p1 = __expf(s1);
      e0 += p0; e1 += p1;
#pragma unroll
      for (int d = 0; d < 8; ++d) { o0[d] = fmaf(p0, vf[d], o0[d]); o1[d] = fmaf(p1, vf[d], o1[d]); }
    }
  }
  const int idx0 = hh * 512 + m0;
  const int idx1 = hh * 512 + m1;
  pE[(size_t)c * 4096 + idx0] = e0;
  pE[(size_t)c * 4096 + idx1] = e1;
  float4* po0 = (float4*)(pO + (size_t)c * 32768 + (size_t)idx0 * 8);
  float4* po1 = (float4*)(pO + (size_t)c * 32768 + (size_t)idx1 * 8);
  po0[0] = make_float4(o0[0], o0[1], o0[2], o0[3]);
  po0[1] = make_float4(o0[4], o0[5], o0[6], o0[7]);
  po1[0] = make_float4(o1[0], o1[1], o1[2], o1[3]);
  po1[1] = make_float4(o1[4], o1[5], o1[6], o1[7]);
}

// ---------------- reduce partials -> oacc / esum ----------------
__global__ __launch_bounds__(256) void kred(const float* __restrict__ pO,
                                            const float* __restrict__ pE,
                                            float* __restrict__ oacc,
                                            float* __restrict__ esum) {
  int gid = blockIdx.x * 256 + threadIdx.x;
  if (gid < 32768) {
    float s = 0.f;
#pragma unroll 8
    for (int ci = 0; ci < NCH; ++ci) s += pO[(size_t)ci * 32768 + gid];
    oacc[gid] = s;
  } else if (gid < 36864) {
    int j = gid - 32768;
    float s = 0.f;
#pragma unroll 8
    for (int ci = 0; ci < NCH; ++ci) s += pE[(size_t)ci * 4096 + j];
    esum[j] = s;
  }
}

// ---------------- attention fallback (atomics) if ws too small ----------
__global__ __launch_bounds__(512) void kattn_atomic(const short* __restrict__ khvh,
                                                    const float* __restrict__ qh,
                                                    float* __restrict__ oacc,
                                                    float* __restrict__ esum) {
  __shared__ short kv[128 * 128];
  const int t = threadIdx.x;
  const int hh = t >> 6;
  const int ms = t & 63;
  {
    const int4* src = (const int4*)(khvh + (size_t)blockIdx.x * 16384);
    int4* d = (int4*)kv;
#pragma unroll
    for (int c = 0; c < 4; ++c) d[t + c * 512] = src[t + c * 512];
  }
  __syncthreads();
  float q[8][8], o[8][8], es[8];
#pragma unroll
  for (int i = 0; i < 8; ++i) {
    const float4* qp = (const float4*)(qh + ((size_t)(ms + i * 64)) * 64 + hh * 8);
    float4 q0 = qp[0], q1 = qp[1];
    q[i][0] = q0.x; q[i][1] = q0.y; q[i][2] = q0.z; q[i][3] = q0.w;
    q[i][4] = q1.x; q[i][5] = q1.y; q[i][6] = q1.z; q[i][7] = q1.w;
    es[i] = 0.f;
#pragma unroll
    for (int d = 0; d < 8; ++d) o[i][d] = 0.f;
  }
  for (int n = 0; n < 128; ++n) {
    const short8 kraw = *(const short8*)(kv + n * 128 + hh * 8);
    const short8 vraw = *(const short8*)(kv + n * 128 + 64 + hh * 8);
    float kf[8], vf[8];
#pragma unroll
    for (int d = 0; d < 8; ++d) {
      kf[d] = bf2f((ushort_t)kraw[d]);
      vf[d] = bf2f((ushort_t)vraw[d]);
    }
#pragma unroll
    for (int i = 0; i < 8; ++i) {
      float s = 0.f;
#pragma unroll
      for (int d = 0; d < 8; ++d) s = fmaf(q[i][d], kf[d], s);
      float p = __expf(s);
      es[i] += p;
#pragma unroll
      for (int d = 0; d < 8; ++d) o[i][d] = fmaf(p, vf[d], o[i][d]);
    }
  }
#pragma unroll
  for (int i = 0; i < 8; ++i) {
    const int m = ms + i * 64;
    atomicAdd(&esum[hh * 512 + m], es[i]);
#pragma unroll
    for (int d = 0; d < 8; ++d) atomicAdd(&oacc[((size_t)(hh * 512 + m)) * 8 + d], o[i][d]);
  }
}

// ---------------- attn_out + ratio ----------------
__global__ __launch_bounds__(256) void kratio(const float* __restrict__ oacc,
                                              const float* __restrict__ esum,
                                              const float* __restrict__ out_w,
                                              const float* __restrict__ out_b,
                                              const float* __restrict__ avg,
                                              float* __restrict__ ratio) {
  int gid = blockIdx.x * 256 + threadIdx.x;  // 32768 = 512*64
  int m = gid >> 6, e = gid & 63;
  float of[64];
#pragma unroll
  for (int h = 0; h < 8; ++h) {
    float inv = 1.f / esum[h * 512 + m];
    const float* op = oacc + ((size_t)(h * 512 + m)) * 8;
#pragma unroll
    for (int d = 0; d < 8; ++d) of[h * 8 + d] = op[d] * inv;
  }
  float a = out_b[e];
  const float* wr = out_w + (size_t)e * 64;
#pragma unroll 8
  for (int j = 0; j < 64; ++j) a = fmaf(of[j], wr[j], a);
  ratio[gid] = 1.f + a / avg[gid];
}

// ---------------- new_mem_w = mem_w * ratio ----------------
__global__ __launch_bounds__(256) void kfinal(const float* __restrict__ mem_w,
                                              const float* __restrict__ ratio,
                                              float* __restrict__ out1) {
  int gid = blockIdx.x * 256 + threadIdx.x;  // 524288 float4s
  float rr = ratio[gid >> 4];
  float4 w = ((const float4*)mem_w)[gid];
  float4 o; o.x = w.x * rr; o.y = w.y * rr; o.z = w.z * rr; o.w = w.w * rr;
  ((float4*)out1)[gid] = o;
}

extern "C" void kernel_launch(void* const* d_in, const int* in_sizes, int n_in,
                              void* d_out, int out_size, void* d_ws, size_t ws_size,
                              hipStream_t stream) {
  (void)in_sizes; (void)n_in; (void)out_size;
  const float* x         = (const float*)d_in[0];
  const float* mem_w     = (const float*)d_in[1];
  const float* ln_g      = (const float*)d_in[2];
  const float* ln_b      = (const float*)d_in[3];
  const float* Wq        = (const float*)d_in[4];
  const float* bq        = (const float*)d_in[5];
  const float* Wk        = (const float*)d_in[6];
  const float* bk        = (const float*)d_in[7];
  const float* Wv        = (const float*)d_in[8];
  const float* bv        = (const float*)d_in[9];
  const float* in_proj_w = (const float*)d_in[10];
  const float* in_proj_b = (const float*)d_in[11];
  const float* out_w     = (const float*)d_in[12];
  const float* out_b     = (const float*)d_in[13];

  float* dout = (float*)d_out;
  char* ws = (char*)d_ws;
  short* wbf   = (short*)(ws + WBF_OFF);
  short* khvh  = (short*)(ws + KVH_OFF);
  float* qh    = (float*)(ws + QH_OFF);
  float* avg   = (float*)(ws + AVG_OFF);
  float* weff  = (float*)(ws + WEFF_OFF);
  float* beff  = (float*)(ws + BEFF_OFF);
  float* oacc  = (float*)(ws + OACC_OFF);
  float* esum  = (float*)(ws + ESUM_OFF);
  float* ratio = (float*)(ws + RATIO_OFF);
  int*   flag  = (int*)(ws + FLAG_OFF);
  float* pO    = (float*)(ws + PO_OFF);
  float* pE    = (float*)(ws + PE_OFF);

  float* mem_out = dout;              // output 0: (32768, 64)
  float* out1    = dout + 2097152;    // output 1: (512, 64, 64)

  const bool use_part = (ws_size >= WS_NEED);   // host-constant: graph-safe

  kinit<<<144, 256, 0, stream>>>(oacc, flag);
  kflag<<<128, 256, 0, stream>>>(ln_g, ln_b, flag);
  kprep<<<128, 256, 0, stream>>>(mem_w, wbf, avg);
  kweff<<<49, 256, 0, stream>>>(in_proj_w, in_proj_b, Wq, bq, Wk, bk, Wv, bv, weff, beff);
  kqh<<<128, 256, 0, stream>>>(avg, weff, beff, qh);
  kscan<<<256, 512, 0, stream>>>(x, wbf, ln_g, ln_b, flag, mem_out);
  kkv<<<256, 256, 0, stream>>>(mem_out, weff, beff, khvh);
  if (use_part) {
    kattn2<<<NCH * 4, 512, 0, stream>>>(khvh, qh, pO, pE);
    kred<<<144, 256, 0, stream>>>(pO, pE, oacc, esum);
  } else {
    kattn_atomic<<<256, 512, 0, stream>>>(khvh, qh, oacc, esum);
  }
  kratio<<<128, 256, 0, stream>>>(oacc, esum, out_w, out_b, avg, ratio);
  kfinal<<<2048, 256, 0, stream>>>(mem_w, ratio, out1);
}

// Round 5
// 595.037 us; speedup vs baseline: 1.7059x; 1.1713x over previous
//
#include <hip/hip_runtime.h>
#include <hip/hip_bf16.h>
#include <cstdint>
#include <cstddef>

typedef __attribute__((ext_vector_type(8))) short short8;
typedef __attribute__((ext_vector_type(4))) float f32x4;
typedef unsigned short ushort_t;

// ---------------- ws layout (bytes) ----------------
#define WBF_OFF   0u            // 512*64*64 bf16 (linear) = 4 MiB
#define KVH_OFF   4194304u      // 32768*128 bf16 (kh|vh per row) = 8 MiB
#define QH_OFF    12582912u     // 512*64 f32 (pre-scaled by 1/sqrt(8))
#define AVG_OFF   12713984u     // 512*64 f32 row means of mem_w
#define WEFF_OFF  12845056u     // 3 * 64*64 f32 combined projections
#define BEFF_OFF  12894208u     // 3 * 64 f32 combined biases
#define OACC_OFF  12894976u     // 8*512*8 f32 attention numerator
#define ESUM_OFF  13026048u     // 8*512 f32 softmax denominator
#define RATIO_OFF 13042432u     // 512*64 f32 (1 + attn_out/row_mean)
#define FLAG_OFF  13173504u     // int: nontrivial ln_g/ln_b flag
#define PO_OFF    13180928u     // 64 chunks * 32768 f32 partial O = 8 MiB
#define PE_OFF    21569536u     // 64 chunks * 4096 f32 partial esum = 1 MiB
#define WS_NEED   22618112ull   // bytes required for the partial scheme
#define NCH 64                  // key chunks (512 keys each)

__device__ __forceinline__ float bf2f(ushort_t u) {
  union { unsigned int i; float f; } c; c.i = ((unsigned int)u) << 16; return c.f;
}
__device__ __forceinline__ unsigned pk2bf(float a, float b) {
  __hip_bfloat162 h = __float22bfloat162_rn(make_float2(a, b));
  unsigned u;
  __builtin_memcpy(&u, &h, 4);
  return u;
}
__device__ __forceinline__ ushort_t f2bf1(float f) {
  union { float f; unsigned int i; } c; c.f = f;
  unsigned int x = c.i;
  x += 0x7FFFu + ((x >> 16) & 1u);
  return (ushort_t)(x >> 16);
}
__device__ __forceinline__ float fbits(unsigned u) { return __builtin_bit_cast(float, u); }
__device__ __forceinline__ unsigned ubits(float f) { return __builtin_bit_cast(unsigned, f); }

// Raw gfx950 register-pair lane swaps (in-place on both operands).
// Direction (odd<->even vs even<->odd) is HW-defined; probed at runtime.
__device__ __forceinline__ void pl16raw(unsigned &a, unsigned &b) {
  asm("v_permlane16_swap_b32 %0, %1" : "+&v"(a), "+&v"(b));
}
__device__ __forceinline__ void pl32raw(unsigned &a, unsigned &b) {
  asm("v_permlane32_swap_b32 %0, %1" : "+&v"(a), "+&v"(b));
}
// Exchange "a's odd 16-rows <-> b's even 16-rows" regardless of HW direction:
// if HW implements the opposite direction (REV=true), call with operands swapped.
template<bool REV> __device__ __forceinline__ void x16(unsigned &a, unsigned &b) {
  if (!REV) pl16raw(a, b); else pl16raw(b, a);
}
template<bool REV> __device__ __forceinline__ void x32(unsigned &a, unsigned &b) {
  if (!REV) pl32raw(a, b); else pl32raw(b, a);
}
// Sum over the 4-lane group {c, c+16, c+32, c+48}; correct under EITHER swap
// direction: with distinct regs holding equal values, a'+b' = pairwise sum.
__device__ __forceinline__ float red4(float v) {
  unsigned a = ubits(v), b = a;
  asm("" : "+v"(b));            // force distinct value/register
  pl16raw(a, b);
  float w = fbits(a) + fbits(b);
  unsigned c = ubits(w), d = c;
  asm("" : "+v"(d));
  pl32raw(c, d);
  return fbits(c) + fbits(d);
}

// ---------------- init: zero accumulators + flag ----------------
__global__ __launch_bounds__(256) void kinit(float* oacc, int* flag) {
  int gid = blockIdx.x * 256 + threadIdx.x;
  if (gid < 36864) oacc[gid] = 0.f;   // oacc (32768) + esum (4096), contiguous
  if (gid == 0) *flag = 0;
}

// ---------------- flag: detect nontrivial ln_g/ln_b ----------------
__global__ __launch_bounds__(256) void kflag(const float* __restrict__ g,
                                             const float* __restrict__ b, int* flag) {
  int gid = blockIdx.x * 256 + threadIdx.x;
  if (gid < 32768) {
    bool bad = (g[gid] != 1.0f) || (b[gid] != 0.0f);
    if (bad) atomicOr(flag, 1);
  }
}

// ---------------- prep: mem_w -> bf16 (linear) + row means ----------------
__global__ __launch_bounds__(256) void kprep(const float* __restrict__ mem_w,
                                             short* __restrict__ wbf,
                                             float* __restrict__ avg) {
  int gid = blockIdx.x * 256 + threadIdx.x;   // row index (m*64 + i), 32768 rows
  const float4* src = (const float4*)(mem_w + (size_t)gid * 64);
  int4* dst = (int4*)(wbf + (size_t)gid * 64);
  float sum = 0.f;
#pragma unroll
  for (int c = 0; c < 8; ++c) {
    float4 f0 = src[c * 2], f1 = src[c * 2 + 1];
    sum += f0.x + f0.y + f0.z + f0.w + f1.x + f1.y + f1.z + f1.w;
    int4 pk;
    pk.x = (int)pk2bf(f0.x, f0.y); pk.y = (int)pk2bf(f0.z, f0.w);
    pk.z = (int)pk2bf(f1.x, f1.y); pk.w = (int)pk2bf(f1.z, f1.w);
    dst[c] = pk;
  }
  avg[gid] = sum * 0.015625f;
}

// ---------------- combined projection weights ----------------
__global__ __launch_bounds__(256) void kweff(const float* __restrict__ in_proj_w,
                                             const float* __restrict__ in_proj_b,
                                             const float* __restrict__ Wq, const float* __restrict__ bq,
                                             const float* __restrict__ Wk, const float* __restrict__ bk,
                                             const float* __restrict__ Wv, const float* __restrict__ bv,
                                             float* __restrict__ weff, float* __restrict__ beff) {
  int gid = blockIdx.x * 256 + threadIdx.x;
  if (gid < 12288) {
    int mat = gid >> 12, j = (gid >> 6) & 63, e = gid & 63;
    const float* Wi = in_proj_w + ((size_t)(mat * 64 + j)) * 64;
    const float* Wx = (mat == 0) ? Wq : ((mat == 1) ? Wk : Wv);
    float acc = 0.f;
#pragma unroll 8
    for (int tt = 0; tt < 64; ++tt) acc = fmaf(Wi[tt], Wx[tt * 64 + e], acc);
    weff[gid] = acc;
  } else if (gid < 12288 + 192) {
    int k = gid - 12288; int mat = k >> 6, j = k & 63;
    const float* Wi = in_proj_w + ((size_t)(mat * 64 + j)) * 64;
    const float* bx = (mat == 0) ? bq : ((mat == 1) ? bk : bv);
    float acc = in_proj_b[mat * 64 + j];
#pragma unroll 8
    for (int tt = 0; tt < 64; ++tt) acc = fmaf(Wi[tt], bx[tt], acc);
    beff[k] = acc;
  }
}

// ---------------- qh = avg_w @ Wq_eff^T + bq_eff, scaled 1/sqrt(DH) --------
__global__ __launch_bounds__(256) void kqh(const float* __restrict__ avg,
                                           const float* __restrict__ weff,
                                           const float* __restrict__ beff,
                                           float* __restrict__ qh) {
  int gid = blockIdx.x * 256 + threadIdx.x;   // 32768 = 512*64
  int m = gid >> 6, j = gid & 63;
  const float* ar = avg + (size_t)m * 64;
  const float* wr = weff + (size_t)j * 64;
  float acc = beff[j];
#pragma unroll 8
  for (int e = 0; e < 64; ++e) acc = fmaf(ar[e], wr[e], acc);
  qh[gid] = acc * 0.35355339059327373f;
}

// ---------------- the sequential memory scan (register-resident h) --------
// 512 thr (8 waves), 128 rows/block. h stays in registers; C-frag -> next
// B-frag via cvt_pk + direction-probed permlane swaps. LDS = W ring only.
#define KSTEP(PP, WFC, WFN, GC, GN)                                            \
  {                                                                            \
    const int m = mb + PP;                                                     \
    if (m + 3 < 512) GN = ((const int4*)wbf)[(m + 3) * 512 + t];               \
    if (m + 1 < 512) {                                                         \
      const char* rb = (const char*)wlds[(PP + 1) & 3];                        \
      _Pragma("unroll")                                                        \
      for (int i = 0; i < 8; ++i) WFN[i] = *(const short8*)(rb + wrd[i]);      \
    }                                                                          \
    f32x4 acc0 = __builtin_amdgcn_mfma_f32_16x16x32_bf16(WFC[0], hf0, z4, 0, 0, 0); \
    f32x4 acc1 = __builtin_amdgcn_mfma_f32_16x16x32_bf16(WFC[2], hf0, z4, 0, 0, 0); \
    f32x4 acc2 = __builtin_amdgcn_mfma_f32_16x16x32_bf16(WFC[4], hf0, z4, 0, 0, 0); \
    f32x4 acc3 = __builtin_amdgcn_mfma_f32_16x16x32_bf16(WFC[6], hf0, z4, 0, 0, 0); \
    acc0 = __builtin_amdgcn_mfma_f32_16x16x32_bf16(WFC[1], hf1, acc0, 0, 0, 0); \
    acc1 = __builtin_amdgcn_mfma_f32_16x16x32_bf16(WFC[3], hf1, acc1, 0, 0, 0); \
    acc2 = __builtin_amdgcn_mfma_f32_16x16x32_bf16(WFC[5], hf1, acc2, 0, 0, 0); \
    acc3 = __builtin_amdgcn_mfma_f32_16x16x32_bf16(WFC[7], hf1, acc3, 0, 0, 0); \
    float s = 0.f, sq = 0.f;                                                   \
    _Pragma("unroll")                                                          \
    for (int rg = 0; rg < 4; ++rg) {                                           \
      float z0 = fmaxf(acc0[rg], 0.f); outv[rg] = z0;                          \
      float z1 = fmaxf(acc1[rg], 0.f); outv[4 + rg] = z1;                      \
      float z2 = fmaxf(acc2[rg], 0.f); outv[8 + rg] = z2;                      \
      float z3 = fmaxf(acc3[rg], 0.f); outv[12 + rg] = z3;                     \
      s += (z0 + z1) + (z2 + z3);                                              \
      sq = fmaf(z0, z0, sq); sq = fmaf(z1, z1, sq);                            \
      sq = fmaf(z2, z2, sq); sq = fmaf(z3, z3, sq);                            \
    }                                                                          \
    s = red4(s); sq = red4(sq);                                                \
    const float mean = s * 0.015625f;                                          \
    const float var = fmaf(sq, 0.015625f, -mean * mean);                       \
    const float rs = rsqrtf(var + 1e-5f);                                      \
    const float cc = -mean * rs;                                               \
    if (gb) {                                                                  \
      _Pragma("unroll")                                                        \
      for (int mt = 0; mt < 4; ++mt) {                                         \
        float4 gg = *(const float4*)(ln_g + m * 64 + mt * 16 + lg * 4);        \
        float4 bb = *(const float4*)(ln_b + m * 64 + mt * 16 + lg * 4);        \
        outv[mt * 4 + 0] = fmaf(fmaf(outv[mt * 4 + 0], rs, cc), gg.x, bb.x);   \
        outv[mt * 4 + 1] = fmaf(fmaf(outv[mt * 4 + 1], rs, cc), gg.y, bb.y);   \
        outv[mt * 4 + 2] = fmaf(fmaf(outv[mt * 4 + 2], rs, cc), gg.z, bb.z);   \
        outv[mt * 4 + 3] = fmaf(fmaf(outv[mt * 4 + 3], rs, cc), gg.w, bb.w);   \
      }                                                                        \
    } else {                                                                   \
      _Pragma("unroll")                                                        \
      for (int i = 0; i < 16; ++i) outv[i] = fmaf(outv[i], rs, cc);            \
    }                                                                          \
    if (m < 511) {                                                             \
      unsigned Q0 = pk2bf(outv[0], outv[1]),   Q1 = pk2bf(outv[2], outv[3]);   \
      unsigned Q2 = pk2bf(outv[4], outv[5]),   Q3 = pk2bf(outv[6], outv[7]);   \
      unsigned Q4 = pk2bf(outv[8], outv[9]),   Q5 = pk2bf(outv[10], outv[11]); \
      unsigned Q6 = pk2bf(outv[12], outv[13]), Q7 = pk2bf(outv[14], outv[15]); \
      x32<R32>(Q0, Q2); x16<R16>(Q0, Q2);                                      \
      x32<R32>(Q1, Q3); x16<R16>(Q1, Q3);                                      \
      x32<R32>(Q4, Q6); x16<R16>(Q4, Q6);                                      \
      x32<R32>(Q5, Q7); x16<R16>(Q5, Q7);                                      \
      union { unsigned d[4]; short8 s8; } uu0, uu1;                            \
      uu0.d[0] = Q0; uu0.d[1] = Q1; uu0.d[2] = Q2; uu0.d[3] = Q3;              \
      uu1.d[0] = Q4; uu1.d[1] = Q5; uu1.d[2] = Q6; uu1.d[3] = Q7;              \
      hf0 = uu0.s8; hf1 = uu1.s8;                                              \
    }                                                                          \
    if (m + 2 < 512) *(int4*)((char*)wlds[(PP + 2) & 3] + so0) = GC;           \
    asm volatile("s_waitcnt lgkmcnt(0)" ::: "memory");                         \
    __builtin_amdgcn_s_barrier();                                              \
  }

template<bool R16, bool R32>
__device__ void kscan_body(const float* __restrict__ x,
                           const short* __restrict__ wbf,
                           const float* __restrict__ ln_g,
                           const float* __restrict__ ln_b,
                           int gb, float* __restrict__ mem_out,
                           short* __restrict__ wldsb) {
  short (*wlds)[64 * 64] = (short (*)[64 * 64])wldsb;
  const int t = threadIdx.x;
  const int lane = t & 63;
  const int wv = t >> 6;
  const int lcol = lane & 15;
  const int lg = lane >> 4;
  const int blk = blockIdx.x;
  const int r = wv * 16 + lcol;          // this lane's h row (0..127)

  const int wsw = (lcol & 7) << 4;
  int wrd[8];                            // A-frag offsets [mt][khalf]
#pragma unroll
  for (int mt = 0; mt < 4; ++mt) {
    wrd[mt * 2]     = mt * 2048 + lcol * 128 + ((lg * 16) ^ wsw);
    wrd[mt * 2 + 1] = mt * 2048 + lcol * 128 + ((lg * 16 + 64) ^ wsw);
  }
  const int so0 = (t * 16) ^ ((((t * 16) >> 7) & 7) << 4);

  // initial h B-fragments straight from x
  short8 hf0, hf1;
  {
    const float4* xr = (const float4*)(x + ((size_t)(blk * 128 + r)) * 64);
    float4 a0 = xr[lg * 2], a1 = xr[lg * 2 + 1];
    float4 b0 = xr[8 + lg * 2], b1 = xr[8 + lg * 2 + 1];
    union { unsigned d[4]; short8 s8; } u0, u1;
    u0.d[0] = pk2bf(a0.x, a0.y); u0.d[1] = pk2bf(a0.z, a0.w);
    u0.d[2] = pk2bf(a1.x, a1.y); u0.d[3] = pk2bf(a1.z, a1.w);
    u1.d[0] = pk2bf(b0.x, b0.y); u1.d[1] = pk2bf(b0.z, b0.w);
    u1.d[2] = pk2bf(b1.x, b1.y); u1.d[3] = pk2bf(b1.z, b1.w);
    hf0 = u0.s8; hf1 = u1.s8;
  }
  // stage W[0] -> buf0, W[1] -> buf1; preload W[2] into a register
  {
    int4 w0 = ((const int4*)wbf)[t];
    int4 w1 = ((const int4*)wbf)[512 + t];
    *(int4*)((char*)wlds[0] + so0) = w0;
    *(int4*)((char*)wlds[1] + so0) = w1;
  }
  int4 g0 = ((const int4*)wbf)[1024 + t];
  int4 g1;
  __syncthreads();

  short8 wfA[8], wfB[8];
#pragma unroll
  for (int i = 0; i < 8; ++i) wfA[i] = *(const short8*)((const char*)wlds[0] + wrd[i]);

  const f32x4 z4 = {0.f, 0.f, 0.f, 0.f};
  float outv[16];

  for (int mb = 0; mb < 512; mb += 4) {
    KSTEP(0, wfA, wfB, g0, g1)
    KSTEP(1, wfB, wfA, g1, g0)
    KSTEP(2, wfA, wfB, g0, g1)
    KSTEP(3, wfB, wfA, g1, g0)
  }

  // epilogue: outv holds the final LN output (f32) for row r
  float* mo = mem_out + ((size_t)(blk * 128 + r)) * 64;
#pragma unroll
  for (int mt = 0; mt < 4; ++mt)
    *(float4*)(mo + mt * 16 + lg * 4) =
        make_float4(outv[mt * 4], outv[mt * 4 + 1], outv[mt * 4 + 2], outv[mt * 4 + 3]);
}

__global__ __launch_bounds__(512, 2) void kscan(
    const float* __restrict__ x, const short* __restrict__ wbf,
    const float* __restrict__ ln_g, const float* __restrict__ ln_b,
    const int* __restrict__ flagp, float* __restrict__ mem_out) {
  __shared__ short wlds[4][64 * 64];     // W ring, bf16, XOR-swizzled, 32 KiB
  const int lane = threadIdx.x & 63;
  const int gb = *flagp;
  // Probe the HW direction of permlane{16,32}_swap (uniform, deterministic).
  unsigned pa = (unsigned)lane, pb = 1000u + (unsigned)lane;
  pl16raw(pa, pb);
  const bool r16 = (__builtin_amdgcn_readfirstlane((int)pa) != 0);
  unsigned qa = (unsigned)lane, qb = 2000u + (unsigned)lane;
  pl32raw(qa, qb);
  const bool r32 = (__builtin_amdgcn_readfirstlane((int)qa) != 0);
  if (!r16) {
    if (!r32) kscan_body<false, false>(x, wbf, ln_g, ln_b, gb, mem_out, &wlds[0][0]);
    else      kscan_body<false, true >(x, wbf, ln_g, ln_b, gb, mem_out, &wlds[0][0]);
  } else {
    if (!r32) kscan_body<true, false >(x, wbf, ln_g, ln_b, gb, mem_out, &wlds[0][0]);
    else      kscan_body<true, true  >(x, wbf, ln_g, ln_b, gb, mem_out, &wlds[0][0]);
  }
}

// ---------------- kh/vh = mem_out @ W{k,v}_eff^T + b, stored bf16 ----------
__global__ __launch_bounds__(256) void kkv(const float* __restrict__ mem_out,
                                           const float* __restrict__ weff,
                                           const float* __restrict__ beff,
                                           short* __restrict__ khvh) {
  __shared__ short kvs[128 * 128];
  const int t = threadIdx.x;
  const int nl = t >> 1;
  const int jh = (t & 1) * 32;
  const int n = blockIdx.x * 128 + nl;
  float mo[64];
  const float4* mop = (const float4*)(mem_out + (size_t)n * 64);
#pragma unroll
  for (int c = 0; c < 16; ++c) {
    float4 f = mop[c];
    mo[c * 4] = f.x; mo[c * 4 + 1] = f.y; mo[c * 4 + 2] = f.z; mo[c * 4 + 3] = f.w;
  }
  const float* wk = weff + 4096;
  const float* wvp = weff + 8192;
  const float* bk = beff + 64;
  const float* bv = beff + 128;
  for (int jj = 0; jj < 32; ++jj) {
    const int j = jh + jj;
    float ak = bk[j], av = bv[j];
    const float* wkr = wk + (size_t)j * 64;
    const float* wvr = wvp + (size_t)j * 64;
#pragma unroll 8
    for (int e = 0; e < 64; ++e) { ak = fmaf(mo[e], wkr[e], ak); av = fmaf(mo[e], wvr[e], av); }
    kvs[nl * 128 + j] = (short)f2bf1(ak);
    kvs[nl * 128 + 64 + j] = (short)f2bf1(av);
  }
  __syncthreads();
  int4* dst = (int4*)(khvh + (size_t)blockIdx.x * 16384);
  const int4* srcl = (const int4*)kvs;
#pragma unroll
  for (int c = 0; c < 8; ++c) dst[t + c * 256] = srcl[t + c * 256];
}

// ---------------- attention, atomic-free two-stage (f32 LDS tiles) --------
__global__ __launch_bounds__(512) void kattn2(const short* __restrict__ khvh,
                                              const float* __restrict__ qh,
                                              float* __restrict__ pO,
                                              float* __restrict__ pE) {
  __shared__ float kvf[64 * 128];   // 64-key tile, f32 (K|V), 32 KiB
  const int t = threadIdx.x;
  const int hh = t >> 6;
  const int ml = t & 63;
  const int c = blockIdx.x >> 2;
  const int mc = blockIdx.x & 3;
  const int m0 = mc * 128 + ml;
  const int m1 = m0 + 64;
  float q0[8], q1[8], o0[8], o1[8];
  float e0 = 0.f, e1 = 0.f;
  {
    const float4* qp0 = (const float4*)(qh + (size_t)m0 * 64 + hh * 8);
    const float4* qp1 = (const float4*)(qh + (size_t)m1 * 64 + hh * 8);
    float4 a = qp0[0], b = qp0[1], cc2 = qp1[0], d2 = qp1[1];
    q0[0]=a.x; q0[1]=a.y; q0[2]=a.z; q0[3]=a.w; q0[4]=b.x; q0[5]=b.y; q0[6]=b.z; q0[7]=b.w;
    q1[0]=cc2.x; q1[1]=cc2.y; q1[2]=cc2.z; q1[3]=cc2.w; q1[4]=d2.x; q1[5]=d2.y; q1[6]=d2.z; q1[7]=d2.w;
#pragma unroll
    for (int d = 0; d < 8; ++d) { o0[d] = 0.f; o1[d] = 0.f; }
  }
  for (int tile = 0; tile < 8; ++tile) {
    if (tile) __syncthreads();
    const int4* src = (const int4*)(khvh + ((size_t)(c * 512 + tile * 64)) * 128);
#pragma unroll
    for (int u = 0; u < 2; ++u) {
      int4 rawv = src[t + u * 512];
      float* dp = kvf + ((size_t)(t + u * 512)) * 8;
      unsigned w0 = (unsigned)rawv.x, w1 = (unsigned)rawv.y;
      unsigned w2 = (unsigned)rawv.z, w3 = (unsigned)rawv.w;
      float4 f0, f1;
      f0.x = bf2f((ushort_t)(w0 & 0xffffu)); f0.y = bf2f((ushort_t)(w0 >> 16));
      f0.z = bf2f((ushort_t)(w1 & 0xffffu)); f0.w = bf2f((ushort_t)(w1 >> 16));
      f1.x = bf2f((ushort_t)(w2 & 0xffffu)); f1.y = bf2f((ushort_t)(w2 >> 16));
      f1.z = bf2f((ushort_t)(w3 & 0xffffu)); f1.w = bf2f((ushort_t)(w3 >> 16));
      *(float4*)dp = f0; *(float4*)(dp + 4) = f1;
    }
    __syncthreads();
    for (int n = 0; n < 64; ++n) {
      const float4 ka = *(const float4*)(kvf + n * 128 + hh * 8);
      const float4 kb = *(const float4*)(kvf + n * 128 + hh * 8 + 4);
      const float4 va = *(const float4*)(kvf + n * 128 + 64 + hh * 8);
      const float4 vb = *(const float4*)(kvf + n * 128 + 64 + hh * 8 + 4);
      float s0 = 0.f, s1 = 0.f;
      s0 = fmaf(q0[0], ka.x, s0); s0 = fmaf(q0[1], ka.y, s0);
      s0 = fmaf(q0[2], ka.z, s0); s0 = fmaf(q0[3], ka.w, s0);
      s0 = fmaf(q0[4], kb.x, s0); s0 = fmaf(q0[5], kb.y, s0);
      s0 = fmaf(q0[6], kb.z, s0); s0 = fmaf(q0[7], kb.w, s0);
      s1 = fmaf(q1[0], ka.x, s1); s1 = fmaf(q1[1], ka.y, s1);
      s1 = fmaf(q1[2], ka.z, s1); s1 = fmaf(q1[3], ka.w, s1);
      s1 = fmaf(q1[4], kb.x, s1); s1 = fmaf(q1[5], kb.y, s1);
      s1 = fmaf(q1[6], kb.z, s1); s1 = fmaf(q1[7], kb.w, s1);
      float p0 = __expf(s0), p1 = __expf(s1);
      e0 += p0; e1 += p1;
      o0[0] = fmaf(p0, va.x, o0[0]); o0[1] = fmaf(p0, va.y, o0[1]);
      o0[2] = fmaf(p0, va.z, o0[2]); o0[3] = fmaf(p0, va.w, o0[3]);
      o0[4] = fmaf(p0, vb.x, o0[4]); o0[5] = fmaf(p0, vb.y, o0[5]);
      o0[6] = fmaf(p0, vb.z, o0[6]); o0[7] = fmaf(p0, vb.w, o0[7]);
      o1[0] = fmaf(p1, va.x, o1[0]); o1[1] = fmaf(p1, va.y, o1[1]);
      o1[2] = fmaf(p1, va.z, o1[2]); o1[3] = fmaf(p1, va.w, o1[3]);
      o1[4] = fmaf(p1, vb.x, o1[4]); o1[5] = fmaf(p1, vb.y, o1[5]);
      o1[6] = fmaf(p1, vb.z, o1[6]); o1[7] = fmaf(p1, vb.w, o1[7]);
    }
  }
  const int idx0 = hh * 512 + m0;
  const int idx1 = hh * 512 + m1;
  pE[(size_t)c * 4096 + idx0] = e0;
  pE[(size_t)c * 4096 + idx1] = e1;
  float4* po0 = (float4*)(pO + (size_t)c * 32768 + (size_t)idx0 * 8);
  float4* po1 = (float4*)(pO + (size_t)c * 32768 + (size_t)idx1 * 8);
  po0[0] = make_float4(o0[0], o0[1], o0[2], o0[3]);
  po0[1] = make_float4(o0[4], o0[5], o0[6], o0[7]);
  po1[0] = make_float4(o1[0], o1[1], o1[2], o1[3]);
  po1[1] = make_float4(o1[4], o1[5], o1[6], o1[7]);
}

// ---------------- reduce partials -> oacc / esum ----------------
__global__ __launch_bounds__(256) void kred(const float* __restrict__ pO,
                                            const float* __restrict__ pE,
                                            float* __restrict__ oacc,
                                            float* __restrict__ esum) {
  int gid = blockIdx.x * 256 + threadIdx.x;
  if (gid < 32768) {
    float s = 0.f;
#pragma unroll 8
    for (int ci = 0; ci < NCH; ++ci) s += pO[(size_t)ci * 32768 + gid];
    oacc[gid] = s;
  } else if (gid < 36864) {
    int j = gid - 32768;
    float s = 0.f;
#pragma unroll 8
    for (int ci = 0; ci < NCH; ++ci) s += pE[(size_t)ci * 4096 + j];
    esum[j] = s;
  }
}

// ---------------- attention fallback (atomics) if ws too small ----------
__global__ __launch_bounds__(512) void kattn_atomic(const short* __restrict__ khvh,
                                                    const float* __restrict__ qh,
                                                    float* __restrict__ oacc,
                                                    float* __restrict__ esum) {
  __shared__ short kv[128 * 128];
  const int t = threadIdx.x;
  const int hh = t >> 6;
  const int ms = t & 63;
  {
    const int4* src = (const int4*)(khvh + (size_t)blockIdx.x * 16384);
    int4* d = (int4*)kv;
#pragma unroll
    for (int c = 0; c < 4; ++c) d[t + c * 512] = src[t + c * 512];
  }
  __syncthreads();
  float q[8][8], o[8][8], es[8];
#pragma unroll
  for (int i = 0; i < 8; ++i) {
    const float4* qp = (const float4*)(qh + ((size_t)(ms + i * 64)) * 64 + hh * 8);
    float4 q0 = qp[0], q1 = qp[1];
    q[i][0] = q0.x; q[i][1] = q0.y; q[i][2] = q0.z; q[i][3] = q0.w;
    q[i][4] = q1.x; q[i][5] = q1.y; q[i][6] = q1.z; q[i][7] = q1.w;
    es[i] = 0.f;
#pragma unroll
    for (int d = 0; d < 8; ++d) o[i][d] = 0.f;
  }
  for (int n = 0; n < 128; ++n) {
    const short8 kraw = *(const short8*)(kv + n * 128 + hh * 8);
    const short8 vraw = *(const short8*)(kv + n * 128 + 64 + hh * 8);
    float kf[8], vf[8];
#pragma unroll
    for (int d = 0; d < 8; ++d) {
      kf[d] = bf2f((ushort_t)kraw[d]);
      vf[d] = bf2f((ushort_t)vraw[d]);
    }
#pragma unroll
    for (int i = 0; i < 8; ++i) {
      float s = 0.f;
#pragma unroll
      for (int d = 0; d < 8; ++d) s = fmaf(q[i][d], kf[d], s);
      float p = __expf(s);
      es[i] += p;
#pragma unroll
      for (int d = 0; d < 8; ++d) o[i][d] = fmaf(p, vf[d], o[i][d]);
    }
  }
#pragma unroll
  for (int i = 0; i < 8; ++i) {
    const int m = ms + i * 64;
    atomicAdd(&esum[hh * 512 + m], es[i]);
#pragma unroll
    for (int d = 0; d < 8; ++d) atomicAdd(&oacc[((size_t)(hh * 512 + m)) * 8 + d], o[i][d]);
  }
}

// ---------------- attn_out + ratio ----------------
__global__ __launch_bounds__(256) void kratio(const float* __restrict__ oacc,
                                              const float* __restrict__ esum,
                                              const float* __restrict__ out_w,
                                              const float* __restrict__ out_b,
                                              const float* __restrict__ avg,
                                              float* __restrict__ ratio) {
  int gid = blockIdx.x * 256 + threadIdx.x;  // 32768 = 512*64
  int m = gid >> 6, e = gid & 63;
  float of[64];
#pragma unroll
  for (int h = 0; h < 8; ++h) {
    float inv = 1.f / esum[h * 512 + m];
    const float* op = oacc + ((size_t)(h * 512 + m)) * 8;
#pragma unroll
    for (int d = 0; d < 8; ++d) of[h * 8 + d] = op[d] * inv;
  }
  float a = out_b[e];
  const float* wr = out_w + (size_t)e * 64;
#pragma unroll 8
  for (int j = 0; j < 64; ++j) a = fmaf(of[j], wr[j], a);
  ratio[gid] = 1.f + a / avg[gid];
}

// ---------------- new_mem_w = mem_w * ratio ----------------
__global__ __launch_bounds__(256) void kfinal(const float* __restrict__ mem_w,
                                              const float* __restrict__ ratio,
                                              float* __restrict__ out1) {
  int gid = blockIdx.x * 256 + threadIdx.x;  // 524288 float4s
  float rr = ratio[gid >> 4];
  float4 w = ((const float4*)mem_w)[gid];
  float4 o; o.x = w.x * rr; o.y = w.y * rr; o.z = w.z * rr; o.w = w.w * rr;
  ((float4*)out1)[gid] = o;
}

extern "C" void kernel_launch(void* const* d_in, const int* in_sizes, int n_in,
                              void* d_out, int out_size, void* d_ws, size_t ws_size,
                              hipStream_t stream) {
  (void)in_sizes; (void)n_in; (void)out_size;
  const float* x         = (const float*)d_in[0];
  const float* mem_w     = (const float*)d_in[1];
  const float* ln_g      = (const float*)d_in[2];
  const float* ln_b      = (const float*)d_in[3];
  const float* Wq        = (const float*)d_in[4];
  const float* bq        = (const float*)d_in[5];
  const float* Wk        = (const float*)d_in[6];
  const float* bk        = (const float*)d_in[7];
  const float* Wv        = (const float*)d_in[8];
  const float* bv        = (const float*)d_in[9];
  const float* in_proj_w = (const float*)d_in[10];
  const float* in_proj_b = (const float*)d_in[11];
  const float* out_w     = (const float*)d_in[12];
  const float* out_b     = (const float*)d_in[13];

  float* dout = (float*)d_out;
  char* ws = (char*)d_ws;
  short* wbf   = (short*)(ws + WBF_OFF);
  short* khvh  = (short*)(ws + KVH_OFF);
  float* qh    = (float*)(ws + QH_OFF);
  float* avg   = (float*)(ws + AVG_OFF);
  float* weff  = (float*)(ws + WEFF_OFF);
  float* beff  = (float*)(ws + BEFF_OFF);
  float* oacc  = (float*)(ws + OACC_OFF);
  float* esum  = (float*)(ws + ESUM_OFF);
  float* ratio = (float*)(ws + RATIO_OFF);
  int*   flag  = (int*)(ws + FLAG_OFF);
  float* pO    = (float*)(ws + PO_OFF);
  float* pE    = (float*)(ws + PE_OFF);

  float* mem_out = dout;              // output 0: (32768, 64)
  float* out1    = dout + 2097152;    // output 1: (512, 64, 64)

  const bool use_part = (ws_size >= WS_NEED);   // host-constant: graph-safe

  kinit<<<144, 256, 0, stream>>>(oacc, flag);
  kflag<<<128, 256, 0, stream>>>(ln_g, ln_b, flag);
  kprep<<<128, 256, 0, stream>>>(mem_w, wbf, avg);
  kweff<<<49, 256, 0, stream>>>(in_proj_w, in_proj_b, Wq, bq, Wk, bk, Wv, bv, weff, beff);
  kqh<<<128, 256, 0, stream>>>(avg, weff, beff, qh);
  kscan<<<256, 512, 0, stream>>>(x, wbf, ln_g, ln_b, flag, mem_out);
  kkv<<<256, 256, 0, stream>>>(mem_out, weff, beff, khvh);
  if (use_part) {
    kattn2<<<NCH * 4, 512, 0, stream>>>(khvh, qh, pO, pE);
    kred<<<144, 256, 0, stream>>>(pO, pE, oacc, esum);
  } else {
    kattn_atomic<<<256, 512, 0, stream>>>(khvh, qh, oacc, esum);
  }
  kratio<<<128, 256, 0, stream>>>(oacc, esum, out_w, out_b, avg, ratio);
  kfinal<<<2048, 256, 0, stream>>>(mem_w, ratio, out1);
}